// Round 4
// baseline (512.952 us; speedup 1.0000x reference)
//
#include <hip/hip_runtime.h>

// Problem constants (B=4, H=W=64, C=256, GROUPS=8)
#define N_TOK 4096          // H*W
#define C_DIM 256
#define BATCH 4
#define M_ROWS (BATCH * N_TOK)   // 16384
#define GN_CNT 131072.0f         // 64*64*32 elements per (b, group)
#define JSPLIT 4                 // attention column chunks (flash-split)

typedef __attribute__((ext_vector_type(4))) float f32x4;
typedef __attribute__((ext_vector_type(16))) float f32x16;
typedef __attribute__((ext_vector_type(8))) short s16x8;      // 8 x bf16 (MFMA A/B frag)
typedef __attribute__((ext_vector_type(4))) unsigned short u16x4;

static __device__ __forceinline__ unsigned short f2bf(float f) {
  unsigned int u = __builtin_bit_cast(unsigned int, f);
  u += 0x7fff + ((u >> 16) & 1);   // RNE
  return (unsigned short)(u >> 16);
}
static __device__ __forceinline__ float bf2f(unsigned short h) {
  unsigned int u = ((unsigned int)h) << 16;
  return __builtin_bit_cast(float, u);
}

// async global->LDS DMA, 16 B per lane; LDS dest = wave-uniform base + lane*16.
static __device__ __forceinline__ void gload_lds16(const void* g, void* l) {
  __builtin_amdgcn_global_load_lds(
      (__attribute__((address_space(1))) void*)(unsigned long long)(const char*)g,
      (__attribute__((address_space(3))) void*)l, 16, 0, 0);
}

// ---------------- weight fp32 -> bf16, transposed: wT[n][k] = w[k][n] ----------
__global__ __launch_bounds__(256) void wtrans(const float* __restrict__ wq,
                                              const float* __restrict__ wk,
                                              const float* __restrict__ wv,
                                              const float* __restrict__ wp,
                                              unsigned short* __restrict__ wT) {
  const float* const srcs[4] = {wq, wk, wv, wp};
  const float* w = srcs[blockIdx.z];
  unsigned short* o = wT + blockIdx.z * 65536;
  __shared__ float t[32][33];
  int k0 = blockIdx.x * 32, n0 = blockIdx.y * 32;
  int tx = threadIdx.x, ty = threadIdx.y;
#pragma unroll
  for (int ky = 0; ky < 32; ky += 8)
    t[ty + ky][tx] = w[(k0 + ty + ky) * C_DIM + n0 + tx];
  __syncthreads();
#pragma unroll
  for (int ky = 0; ky < 32; ky += 8)
    o[(n0 + ty + ky) * C_DIM + k0 + tx] = f2bf(t[tx][ty + ky]);
}

// ---------------- GroupNorm partial stats -> atomics into ws ------------------
__global__ __launch_bounds__(256) void gn_stats(const float* __restrict__ x,
                                                float* __restrict__ partials) {
  int bg = blockIdx.x >> 4, chunk = blockIdx.x & 15;
  int b = bg >> 3, g = bg & 7;
  int tid = threadIdx.x;
  const f32x4* x4 = (const f32x4*)x;
  float s1 = 0.f, s2 = 0.f;
#pragma unroll
  for (int it = 0; it < 8; ++it) {
    int idx = it * 256 + tid;
    int nl = idx >> 3, cq = idx & 7;
    f32x4 v = x4[(b * N_TOK + chunk * 256 + nl) * 64 + g * 8 + cq];
    s1 += v[0] + v[1] + v[2] + v[3];
    s2 += v[0] * v[0] + v[1] * v[1] + v[2] * v[2] + v[3] * v[3];
  }
  for (int m = 1; m < 64; m <<= 1) {
    s1 += __shfl_xor(s1, m, 64);
    s2 += __shfl_xor(s2, m, 64);
  }
  __shared__ float r1[4], r2[4];
  int wave = tid >> 6, lane = tid & 63;
  if (lane == 0) { r1[wave] = s1; r2[wave] = s2; }
  __syncthreads();
  if (tid == 0) {
    atomicAdd(&partials[bg * 2],     r1[0] + r1[1] + r1[2] + r1[3]);
    atomicAdd(&partials[bg * 2 + 1], r2[0] + r2[1] + r2[2] + r2[3]);
  }
}

// ---------------- GroupNorm normalize -> bf16 xn ------------------------------
__global__ __launch_bounds__(256) void gn_norm(const float* __restrict__ x,
                                               const float* __restrict__ gamma,
                                               const float* __restrict__ beta,
                                               const float* __restrict__ partials,
                                               unsigned short* __restrict__ xn) {
  const f32x4* x4 = (const f32x4*)x;
  const f32x4* g4 = (const f32x4*)gamma;
  const f32x4* b4 = (const f32x4*)beta;
  u16x4* o4 = (u16x4*)xn;
  int t0 = blockIdx.x * 256 + threadIdx.x;
#pragma unroll
  for (int it = 0; it < 4; ++it) {
    int fid = it * 262144 + t0;
    int row = fid >> 6, c4 = fid & 63;
    int b = row >> 12, g = c4 >> 3;
    int bg = b * 8 + g;
    float inv = 1.f / GN_CNT;
    float mean = partials[bg * 2] * inv;
    float var = partials[bg * 2 + 1] * inv - mean * mean;
    float rstd = rsqrtf(var + 1e-3f);
    f32x4 v = x4[fid], ga = g4[c4], be = b4[c4];
    u16x4 o;
#pragma unroll
    for (int j = 0; j < 4; ++j) o[j] = f2bf((v[j] - mean) * rstd * ga[j] + be[j]);
    o4[fid] = o;
  }
}

// ---------------- QKV GEMM: [16384,256] @ [256,256] + bias -> bf16 ------------
__global__ __launch_bounds__(256) void qkv_gemm(const unsigned short* __restrict__ xn,
                                                const unsigned short* __restrict__ wT,
                                                const float* __restrict__ bq,
                                                const float* __restrict__ bk,
                                                const float* __restrict__ bv,
                                                unsigned short* __restrict__ qo,
                                                unsigned short* __restrict__ ko,
                                                unsigned short* __restrict__ vo) {
  int tid = threadIdx.x;
  int wave = tid >> 6, lane = tid & 63, g = lane >> 4, c16 = lane & 15;
  int row0 = blockIdx.x * 64 + wave * 16;
  int w = blockIdx.y;
  s16x8 af[8];
#pragma unroll
  for (int s = 0; s < 8; ++s)
    af[s] = *(const s16x8*)(xn + (row0 + c16) * C_DIM + s * 32 + g * 8);
  const float* bias = (w == 0) ? bq : (w == 1) ? bk : bv;
  unsigned short* outp = (w == 0) ? qo : (w == 1) ? ko : vo;
  float scale = (w == 0) ? 0.0625f : 1.f;   // q absorbs softmax scale C^-0.5
  const unsigned short* wt = wT + w * 65536;
  for (int ct = 0; ct < 16; ++ct) {
    float bv0 = bias[ct * 16 + c16];
    f32x4 acc = {bv0, bv0, bv0, bv0};
#pragma unroll
    for (int s = 0; s < 8; ++s) {
      s16x8 bf = *(const s16x8*)(wt + (ct * 16 + c16) * C_DIM + s * 32 + g * 8);
      acc = __builtin_amdgcn_mfma_f32_16x16x32_bf16(af[s], bf, acc, 0, 0, 0);
    }
#pragma unroll
    for (int r = 0; r < 4; ++r)
      outp[(row0 + g * 4 + r) * C_DIM + ct * 16 + c16] = f2bf(acc[r] * scale);
  }
}

// ---------------- V transpose: v[b][n][c] -> vT[b][c][n] ----------------------
__global__ __launch_bounds__(256) void vtrans(const unsigned short* __restrict__ v,
                                              unsigned short* __restrict__ vT) {
  __shared__ unsigned short t[32][33];
  int n0 = blockIdx.x * 32, c0 = blockIdx.y * 32, b = blockIdx.z;
  int tx = threadIdx.x, ty = threadIdx.y;
#pragma unroll
  for (int ky = 0; ky < 32; ky += 8)
    t[ty + ky][tx] = v[(b * N_TOK + n0 + ty + ky) * C_DIM + c0 + tx];
  __syncthreads();
#pragma unroll
  for (int ky = 0; ky < 32; ky += 8)
    vT[(b * C_DIM + c0 + ty + ky) * N_TOK + n0 + tx] = t[tx][ty + ky];
}

// ---------------- Flash attention partial: 32x32 MFMA, fixed-max softmax ------
// 512 blocks (2/CU), 4 waves x 32 Q-rows = 128 rows/block, chunk = 1024 cols in
// 16 j-tiles of 64. K(64x256)+V(256x64) staged via global_load_lds w=16 with
// source-side XOR swizzle so all ds_read_b128 are conflict-free. Fixed-max
// softmax p=exp(s-8): no running max/rescale; per-lane l partial sums reduced
// once at the end. P lives in a dedicated per-wave LDS region (80KB total).
__global__ __launch_bounds__(256, 2) void attn_part(const unsigned short* __restrict__ q,
                                                    const unsigned short* __restrict__ k,
                                                    const unsigned short* __restrict__ vT,
                                                    unsigned short* __restrict__ op0,
                                                    unsigned short* __restrict__ op1,
                                                    unsigned short* __restrict__ op2,
                                                    unsigned short* __restrict__ op3,
                                                    float* __restrict__ lbuf) {
  int tid = threadIdx.x;
  int wave = tid >> 6, lane = tid & 63;
  int n32 = lane & 31, half = lane >> 5;
  // batch -> XCD-pair swizzle (XCD = blockIdx%8 heuristic)
  int i = blockIdx.x;                        // 0..511
  int batch = (i >> 1) & 3;
  int slot = ((i >> 3) << 1) | (i & 1);      // 0..127
  int qb = slot & 31, chunk = slot >> 5;     // 32 row-blocks x 4 chunks
  int qrow0 = batch * N_TOK + qb * 128 + wave * 32;
  const unsigned short* kb = k + (size_t)batch * N_TOK * C_DIM;
  const unsigned short* vb = vT + (size_t)batch * C_DIM * N_TOK;
  unsigned short* op = (chunk == 0) ? op0 : (chunk == 1) ? op1 : (chunk == 2) ? op2 : op3;

  __shared__ __align__(16) unsigned short Kt[16384];   // 64 tok x 256 ch (swizzled)
  __shared__ __align__(16) unsigned short Vt[16384];   // 256 ch x 64 j (swizzled)
  __shared__ __align__(16) unsigned short Pt[4][2048]; // per-wave 32 x 64 (swizzled)
  unsigned short* myp = Pt[wave];

  s16x8 qf[16];
#pragma unroll
  for (int ks = 0; ks < 16; ++ks)
    qf[ks] = *(const s16x8*)(q + (size_t)(qrow0 + n32) * C_DIM + ks * 16 + half * 8);

  f32x16 Oa[8];
#pragma unroll
  for (int ct = 0; ct < 8; ++ct) Oa[ct] = (f32x16)(0.f);
  float ls[16];
#pragma unroll
  for (int r = 0; r < 16; ++r) ls[r] = 0.f;

  for (int jt = 0; jt < 16; ++jt) {
    int jbase = chunk * 1024 + jt * 64;
    // stage K: 2048 16B-units, source-swizzled (^ tok&7 on the ch-unit)
#pragma unroll
    for (int ii = 0; ii < 8; ++ii) {
      int u = ii * 256 + tid;
      int tok = u >> 5, un = u & 31;
      gload_lds16(kb + (size_t)(jbase + tok) * C_DIM + ((un ^ (tok & 7)) * 8), Kt + u * 8);
    }
    // stage V: 2048 16B-units (rows of vT), source-swizzled (^ ch&7)
#pragma unroll
    for (int ii = 0; ii < 8; ++ii) {
      int u = ii * 256 + tid;
      int ch = u >> 3, un = u & 7;
      gload_lds16(vb + (size_t)ch * N_TOK + jbase + ((un ^ (ch & 7)) * 8), Vt + u * 8);
    }
    __syncthreads();

    // QK^T + exp + P write, one 32x32 S-tile at a time
#pragma unroll
    for (int t = 0; t < 2; ++t) {
      f32x16 sc = (f32x16)(0.f);
      int tok = t * 32 + n32;
      const unsigned short* kbase = Kt + tok * 256;
      int trh = tok & 7;
#pragma unroll
      for (int ks = 0; ks < 16; ++ks) {
        s16x8 kf = *(const s16x8*)(kbase + (((ks * 2 + half) ^ trh) * 8));
        sc = __builtin_amdgcn_mfma_f32_32x32x16_bf16(qf[ks], kf, sc, 0, 0, 0);
      }
#pragma unroll
      for (int r = 0; r < 16; ++r) {
        float p = exp2f(fmaf(sc[r], 1.44269504f, -11.54156032f));  // exp(s-8)
        ls[r] += p;
        int row = (r & 3) + 8 * (r >> 2) + 4 * half;
        int j = t * 32 + n32;
        myp[row * 64 + (((j >> 3) ^ (row & 7)) * 8) + (j & 7)] = f2bf(p);
      }
    }
    // P A-frags (wave-private, in-order DS)
    s16x8 pf[4];
    int prh = n32 & 7;
#pragma unroll
    for (int ks = 0; ks < 4; ++ks)
      pf[ks] = *(const s16x8*)(myp + n32 * 64 + (((ks * 2 + half) ^ prh) * 8));
    // PV: O[32 x 256] += P[32 x 64] @ V[64 x 256]
#pragma unroll
    for (int ct = 0; ct < 8; ++ct) {
      int ch = ct * 32 + n32;
      const unsigned short* vbase = Vt + ch * 64;
      int crh = ch & 7;
#pragma unroll
      for (int ks = 0; ks < 4; ++ks) {
        s16x8 vf = *(const s16x8*)(vbase + (((ks * 2 + half) ^ crh) * 8));
        Oa[ct] = __builtin_amdgcn_mfma_f32_32x32x16_bf16(pf[ks], vf, Oa[ct], 0, 0, 0);
      }
    }
    __syncthreads();   // all reads done before next stage overwrites
  }
  // epilogue: unnormalized O (bf16) + row sums l
#pragma unroll
  for (int ct = 0; ct < 8; ++ct)
#pragma unroll
    for (int r = 0; r < 16; ++r) {
      int row = (r & 3) + 8 * (r >> 2) + 4 * half;
      op[(size_t)(qrow0 + row) * C_DIM + ct * 32 + n32] = f2bf(Oa[ct][r]);
    }
#pragma unroll
  for (int r = 0; r < 16; ++r) {
    float v = ls[r];
    v += __shfl_xor(v, 1); v += __shfl_xor(v, 2); v += __shfl_xor(v, 4);
    v += __shfl_xor(v, 8); v += __shfl_xor(v, 16);
    if (n32 == 0) {
      int row = (r & 3) + 8 * (r >> 2) + 4 * half;
      lbuf[chunk * M_ROWS + qrow0 + row] = v;
    }
  }
}

// ------- Output projection (fused combine) + bias + residual -> fp32 out ------
// A = (sum of 4 unnormalized O planes) / (sum of 4 l partials), built in regs.
__global__ __launch_bounds__(256) void proj_gemm(const unsigned short* __restrict__ p0,
                                                 const unsigned short* __restrict__ p1,
                                                 const unsigned short* __restrict__ p2,
                                                 const unsigned short* __restrict__ p3,
                                                 const float* __restrict__ lbuf,
                                                 const unsigned short* __restrict__ wt,
                                                 const float* __restrict__ bp,
                                                 const float* __restrict__ x,
                                                 float* __restrict__ out) {
  int tid = threadIdx.x;
  int wave = tid >> 6, lane = tid & 63, g = lane >> 4, c16 = lane & 15;
  int row0 = blockIdx.x * 64 + wave * 16;
  int ct0 = blockIdx.y * 8;
  int row = row0 + c16;
  float linv = 1.f / (lbuf[row] + lbuf[M_ROWS + row] +
                      lbuf[2 * M_ROWS + row] + lbuf[3 * M_ROWS + row]);
  s16x8 af[8];
#pragma unroll
  for (int s = 0; s < 8; ++s) {
    size_t off = (size_t)row * C_DIM + s * 32 + g * 8;
    s16x8 a0 = *(const s16x8*)(p0 + off);
    s16x8 a1 = *(const s16x8*)(p1 + off);
    s16x8 a2 = *(const s16x8*)(p2 + off);
    s16x8 a3 = *(const s16x8*)(p3 + off);
    s16x8 o;
#pragma unroll
    for (int j = 0; j < 8; ++j) {
      float f = bf2f((unsigned short)a0[j]) + bf2f((unsigned short)a1[j]) +
                bf2f((unsigned short)a2[j]) + bf2f((unsigned short)a3[j]);
      o[j] = (short)f2bf(f * linv);
    }
    af[s] = o;
  }
  for (int ct = ct0; ct < ct0 + 8; ++ct) {
    float bias = bp[ct * 16 + c16];
    f32x4 acc = {bias, bias, bias, bias};
#pragma unroll
    for (int s = 0; s < 8; ++s) {
      s16x8 bf = *(const s16x8*)(wt + (ct * 16 + c16) * C_DIM + s * 32 + g * 8);
      acc = __builtin_amdgcn_mfma_f32_16x16x32_bf16(af[s], bf, acc, 0, 0, 0);
    }
#pragma unroll
    for (int r = 0; r < 4; ++r) {
      int idx = (row0 + g * 4 + r) * C_DIM + ct * 16 + c16;
      out[idx] = acc[r] + x[idx];
    }
  }
}

extern "C" void kernel_launch(void* const* d_in, const int* in_sizes, int n_in,
                              void* d_out, int out_size, void* d_ws, size_t ws_size,
                              hipStream_t stream) {
  const float* x     = (const float*)d_in[0];
  const float* gamma = (const float*)d_in[1];
  const float* beta  = (const float*)d_in[2];
  const float* wq    = (const float*)d_in[3];
  const float* bq    = (const float*)d_in[4];
  const float* wk    = (const float*)d_in[5];
  const float* bk    = (const float*)d_in[6];
  const float* wv    = (const float*)d_in[7];
  const float* bv    = (const float*)d_in[8];
  const float* wp    = (const float*)d_in[9];
  const float* bp    = (const float*)d_in[10];
  float* out = (float*)d_out;

  char* ws = (char*)d_ws;
  const size_t MC = (size_t)M_ROWS * C_DIM;
  float* partials      = (float*)ws;                          // 64 floats
  unsigned short* wT   = (unsigned short*)(ws + 1024);        // 4 x 256x256 bf16
  unsigned short* xnb  = wT + 4 * 65536;                      // xn bf16 [16384,256]
  unsigned short* qb   = xnb + MC;
  unsigned short* kbuf = qb + MC;
  unsigned short* vb   = kbuf + MC;
  unsigned short* vTb  = vb + MC;
  unsigned short* exA  = vTb + MC;                            // O partial planes 2,3
  unsigned short* exB  = exA + MC;
  float* lbuf          = (float*)(exB + MC);                  // 4 x 16384 floats
  // O partial planes: 0 -> xnb (dead after qkv), 1 -> vb (dead after vtrans)
  unsigned short* plane0 = xnb;
  unsigned short* plane1 = vb;

  hipMemsetAsync(partials, 0, 64 * sizeof(float), stream);
  wtrans<<<dim3(8, 8, 4), dim3(32, 8), 0, stream>>>(wq, wk, wv, wp, wT);
  gn_stats<<<512, 256, 0, stream>>>(x, partials);
  gn_norm<<<1024, 256, 0, stream>>>(x, gamma, beta, partials, xnb);
  qkv_gemm<<<dim3(256, 3), 256, 0, stream>>>(xnb, wT, bq, bk, bv, qb, kbuf, vb);
  vtrans<<<dim3(128, 8, 4), dim3(32, 8), 0, stream>>>(vb, vTb);
  attn_part<<<512, 256, 0, stream>>>(qb, kbuf, vTb, plane0, plane1, exA, exB, lbuf);
  proj_gemm<<<dim3(256, 2), 256, 0, stream>>>(plane0, plane1, exA, exB, lbuf,
                                              wT + 3 * 65536, bp, x, out);
}

// Round 5
// 317.701 us; speedup vs baseline: 1.6146x; 1.6146x over previous
//
#include <hip/hip_runtime.h>

// Problem constants (B=4, H=W=64, C=256, GROUPS=8)
#define N_TOK 4096          // H*W
#define C_DIM 256
#define BATCH 4
#define M_ROWS (BATCH * N_TOK)   // 16384
#define GN_CNT 131072.0f         // 64*64*32 elements per (b, group)
#define JSPLIT 4                 // attention column chunks (flash-split)

typedef __attribute__((ext_vector_type(4))) float f32x4;
typedef __attribute__((ext_vector_type(16))) float f32x16;
typedef __attribute__((ext_vector_type(8))) short s16x8;      // 8 x bf16 (MFMA A/B frag)
typedef __attribute__((ext_vector_type(4))) unsigned short u16x4;

static __device__ __forceinline__ unsigned short f2bf(float f) {
  unsigned int u = __builtin_bit_cast(unsigned int, f);
  u += 0x7fff + ((u >> 16) & 1);   // RNE
  return (unsigned short)(u >> 16);
}
static __device__ __forceinline__ float bf2f(unsigned short h) {
  unsigned int u = ((unsigned int)h) << 16;
  return __builtin_bit_cast(float, u);
}

// async global->LDS DMA, 16 B per lane; LDS dest = wave-uniform base + lane*16.
static __device__ __forceinline__ void gload_lds16(const void* g, void* l) {
  __builtin_amdgcn_global_load_lds(
      (__attribute__((address_space(1))) void*)(unsigned long long)(const char*)g,
      (__attribute__((address_space(3))) void*)l, 16, 0, 0);
}

// ---------------- weight fp32 -> bf16, transposed: wT[n][k] = w[k][n] ----------
__global__ __launch_bounds__(256) void wtrans(const float* __restrict__ wq,
                                              const float* __restrict__ wk,
                                              const float* __restrict__ wv,
                                              const float* __restrict__ wp,
                                              unsigned short* __restrict__ wT) {
  const float* const srcs[4] = {wq, wk, wv, wp};
  const float* w = srcs[blockIdx.z];
  unsigned short* o = wT + blockIdx.z * 65536;
  __shared__ float t[32][33];
  int k0 = blockIdx.x * 32, n0 = blockIdx.y * 32;
  int tx = threadIdx.x, ty = threadIdx.y;
#pragma unroll
  for (int ky = 0; ky < 32; ky += 8)
    t[ty + ky][tx] = w[(k0 + ty + ky) * C_DIM + n0 + tx];
  __syncthreads();
#pragma unroll
  for (int ky = 0; ky < 32; ky += 8)
    o[(n0 + ty + ky) * C_DIM + k0 + tx] = f2bf(t[tx][ty + ky]);
}

// ---------------- GroupNorm partial stats -> atomics into ws ------------------
__global__ __launch_bounds__(256) void gn_stats(const float* __restrict__ x,
                                                float* __restrict__ partials) {
  int bg = blockIdx.x >> 4, chunk = blockIdx.x & 15;
  int b = bg >> 3, g = bg & 7;
  int tid = threadIdx.x;
  const f32x4* x4 = (const f32x4*)x;
  float s1 = 0.f, s2 = 0.f;
#pragma unroll
  for (int it = 0; it < 8; ++it) {
    int idx = it * 256 + tid;
    int nl = idx >> 3, cq = idx & 7;
    f32x4 v = x4[(b * N_TOK + chunk * 256 + nl) * 64 + g * 8 + cq];
    s1 += v[0] + v[1] + v[2] + v[3];
    s2 += v[0] * v[0] + v[1] * v[1] + v[2] * v[2] + v[3] * v[3];
  }
  for (int m = 1; m < 64; m <<= 1) {
    s1 += __shfl_xor(s1, m, 64);
    s2 += __shfl_xor(s2, m, 64);
  }
  __shared__ float r1[4], r2[4];
  int wave = tid >> 6, lane = tid & 63;
  if (lane == 0) { r1[wave] = s1; r2[wave] = s2; }
  __syncthreads();
  if (tid == 0) {
    atomicAdd(&partials[bg * 2],     r1[0] + r1[1] + r1[2] + r1[3]);
    atomicAdd(&partials[bg * 2 + 1], r2[0] + r2[1] + r2[2] + r2[3]);
  }
}

// ---------------- GroupNorm normalize -> bf16 xn ------------------------------
__global__ __launch_bounds__(256) void gn_norm(const float* __restrict__ x,
                                               const float* __restrict__ gamma,
                                               const float* __restrict__ beta,
                                               const float* __restrict__ partials,
                                               unsigned short* __restrict__ xn) {
  const f32x4* x4 = (const f32x4*)x;
  const f32x4* g4 = (const f32x4*)gamma;
  const f32x4* b4 = (const f32x4*)beta;
  u16x4* o4 = (u16x4*)xn;
  int t0 = blockIdx.x * 256 + threadIdx.x;
#pragma unroll
  for (int it = 0; it < 4; ++it) {
    int fid = it * 262144 + t0;
    int row = fid >> 6, c4 = fid & 63;
    int b = row >> 12, g = c4 >> 3;
    int bg = b * 8 + g;
    float inv = 1.f / GN_CNT;
    float mean = partials[bg * 2] * inv;
    float var = partials[bg * 2 + 1] * inv - mean * mean;
    float rstd = rsqrtf(var + 1e-3f);
    f32x4 v = x4[fid], ga = g4[c4], be = b4[c4];
    u16x4 o;
#pragma unroll
    for (int j = 0; j < 4; ++j) o[j] = f2bf((v[j] - mean) * rstd * ga[j] + be[j]);
    o4[fid] = o;
  }
}

// ---------------- QKV GEMM: [16384,256] @ [256,256] + bias -> bf16 ------------
__global__ __launch_bounds__(256) void qkv_gemm(const unsigned short* __restrict__ xn,
                                                const unsigned short* __restrict__ wT,
                                                const float* __restrict__ bq,
                                                const float* __restrict__ bk,
                                                const float* __restrict__ bv,
                                                unsigned short* __restrict__ qo,
                                                unsigned short* __restrict__ ko,
                                                unsigned short* __restrict__ vo) {
  int tid = threadIdx.x;
  int wave = tid >> 6, lane = tid & 63, g = lane >> 4, c16 = lane & 15;
  int row0 = blockIdx.x * 64 + wave * 16;
  int w = blockIdx.y;
  s16x8 af[8];
#pragma unroll
  for (int s = 0; s < 8; ++s)
    af[s] = *(const s16x8*)(xn + (row0 + c16) * C_DIM + s * 32 + g * 8);
  const float* bias = (w == 0) ? bq : (w == 1) ? bk : bv;
  unsigned short* outp = (w == 0) ? qo : (w == 1) ? ko : vo;
  float scale = (w == 0) ? 0.0625f : 1.f;   // q absorbs softmax scale C^-0.5
  const unsigned short* wt = wT + w * 65536;
  for (int ct = 0; ct < 16; ++ct) {
    float bv0 = bias[ct * 16 + c16];
    f32x4 acc = {bv0, bv0, bv0, bv0};
#pragma unroll
    for (int s = 0; s < 8; ++s) {
      s16x8 bf = *(const s16x8*)(wt + (ct * 16 + c16) * C_DIM + s * 32 + g * 8);
      acc = __builtin_amdgcn_mfma_f32_16x16x32_bf16(af[s], bf, acc, 0, 0, 0);
    }
#pragma unroll
    for (int r = 0; r < 4; ++r)
      outp[(row0 + g * 4 + r) * C_DIM + ct * 16 + c16] = f2bf(acc[r] * scale);
  }
}

// ---------------- V transpose: v[b][n][c] -> vT[b][c][n] ----------------------
__global__ __launch_bounds__(256) void vtrans(const unsigned short* __restrict__ v,
                                              unsigned short* __restrict__ vT) {
  __shared__ unsigned short t[32][33];
  int n0 = blockIdx.x * 32, c0 = blockIdx.y * 32, b = blockIdx.z;
  int tx = threadIdx.x, ty = threadIdx.y;
#pragma unroll
  for (int ky = 0; ky < 32; ky += 8)
    t[ty + ky][tx] = v[(b * N_TOK + n0 + ty + ky) * C_DIM + c0 + tx];
  __syncthreads();
#pragma unroll
  for (int ky = 0; ky < 32; ky += 8)
    vT[(b * C_DIM + c0 + ty + ky) * N_TOK + n0 + tx] = t[tx][ty + ky];
}

// ---------------- Flash attention partial: 32x32 MFMA, fixed-max softmax ------
// 512 blocks (2/CU), 4 waves x 32 Q-rows = 128 rows/block, chunk = 1024 cols in
// 16 j-tiles of 64. Register budget fix vs R4: Q A-frags are reloaded from
// global (L1/L2-resident) EVERY jt instead of living in 64 VGPRs; an empty asm
// on the pointer blocks LICM so the compiler can't hoist them back. Peak
// pressure ~205 regs (Oa 128 AGPR + ~75 VGPR) -> no scratch spill at
// launch_bounds(256,2). QK^T is ks-outer so each Q frag feeds both S-tiles.
__global__ __launch_bounds__(256, 2) void attn_part(const unsigned short* __restrict__ q,
                                                    const unsigned short* __restrict__ k,
                                                    const unsigned short* __restrict__ vT,
                                                    unsigned short* __restrict__ op0,
                                                    unsigned short* __restrict__ op1,
                                                    unsigned short* __restrict__ op2,
                                                    unsigned short* __restrict__ op3,
                                                    float* __restrict__ lbuf) {
  int tid = threadIdx.x;
  int wave = tid >> 6, lane = tid & 63;
  int n32 = lane & 31, half = lane >> 5;
  // batch -> XCD-pair swizzle (XCD = blockIdx%8 heuristic)
  int i = blockIdx.x;                        // 0..511
  int batch = (i >> 1) & 3;
  int slot = ((i >> 3) << 1) | (i & 1);      // 0..127
  int qb = slot & 31, chunk = slot >> 5;     // 32 row-blocks x 4 chunks
  int qrow0 = batch * N_TOK + qb * 128 + wave * 32;
  const unsigned short* kb = k + (size_t)batch * N_TOK * C_DIM;
  const unsigned short* vb = vT + (size_t)batch * C_DIM * N_TOK;
  unsigned short* op = (chunk == 0) ? op0 : (chunk == 1) ? op1 : (chunk == 2) ? op2 : op3;

  __shared__ __align__(16) unsigned short Kt[16384];   // 64 tok x 256 ch (swizzled)
  __shared__ __align__(16) unsigned short Vt[16384];   // 256 ch x 64 j (swizzled)
  __shared__ __align__(16) unsigned short Pt[4][2048]; // per-wave 32 x 64 (swizzled)
  unsigned short* myp = Pt[wave];

  const unsigned short* qp = q + (size_t)(qrow0 + n32) * C_DIM;  // lane's Q row

  f32x16 Oa[8];
#pragma unroll
  for (int ct = 0; ct < 8; ++ct) Oa[ct] = (f32x16)(0.f);
  float ls[16];
#pragma unroll
  for (int r = 0; r < 16; ++r) ls[r] = 0.f;

  int trh = n32 & 7;                         // tok&7 for both S-tiles (32 = 0 mod 8)
  const unsigned short* kbase0 = Kt + n32 * 256;
  const unsigned short* kbase1 = Kt + (32 + n32) * 256;

  for (int jt = 0; jt < 16; ++jt) {
    int jbase = chunk * 1024 + jt * 64;
    // stage K: 2048 16B-units, source-swizzled (^ tok&7 on the ch-unit)
#pragma unroll
    for (int ii = 0; ii < 8; ++ii) {
      int u = ii * 256 + tid;
      int tok = u >> 5, un = u & 31;
      gload_lds16(kb + (size_t)(jbase + tok) * C_DIM + ((un ^ (tok & 7)) * 8), Kt + u * 8);
    }
    // stage V: 2048 16B-units (rows of vT), source-swizzled (^ ch&7)
#pragma unroll
    for (int ii = 0; ii < 8; ++ii) {
      int u = ii * 256 + tid;
      int ch = u >> 3, un = u & 7;
      gload_lds16(vb + (size_t)ch * N_TOK + jbase + ((un ^ (ch & 7)) * 8), Vt + u * 8);
    }
    __syncthreads();

    // Q pointer made loop-variant-opaque: blocks LICM (Q frags reload per jt
    // from L1/L2 instead of occupying 64 VGPRs for the whole kernel).
    const unsigned short* qj = qp;
    asm volatile("" : "+v"(qj));

    // QK^T: both 32x32 S-tiles, ks-outer so each Q frag is loaded once
    f32x16 sc0 = (f32x16)(0.f), sc1 = (f32x16)(0.f);
#pragma unroll
    for (int ks = 0; ks < 16; ++ks) {
      s16x8 qf = *(const s16x8*)(qj + ks * 16 + half * 8);
      int u = (((ks * 2 + half) ^ trh) * 8);
      s16x8 kf0 = *(const s16x8*)(kbase0 + u);
      s16x8 kf1 = *(const s16x8*)(kbase1 + u);
      sc0 = __builtin_amdgcn_mfma_f32_32x32x16_bf16(qf, kf0, sc0, 0, 0, 0);
      sc1 = __builtin_amdgcn_mfma_f32_32x32x16_bf16(qf, kf1, sc1, 0, 0, 0);
    }
    // exp(s-8) fused with P LDS write (no p[] array -> low reg pressure)
#pragma unroll
    for (int r = 0; r < 16; ++r) {
      int row = (r & 3) + 8 * (r >> 2) + 4 * half;
      int rh = row & 7;
      float p0 = exp2f(fmaf(sc0[r], 1.44269504f, -11.54156032f));
      ls[r] += p0;
      myp[row * 64 + (((n32 >> 3) ^ rh) * 8) + (n32 & 7)] = f2bf(p0);
      float p1 = exp2f(fmaf(sc1[r], 1.44269504f, -11.54156032f));
      ls[r] += p1;
      myp[row * 64 + (((4 + (n32 >> 3)) ^ rh) * 8) + (n32 & 7)] = f2bf(p1);
    }
    // P A-frags (wave-private, in-order DS)
    s16x8 pf[4];
    int prh = n32 & 7;
#pragma unroll
    for (int ks = 0; ks < 4; ++ks)
      pf[ks] = *(const s16x8*)(myp + n32 * 64 + (((ks * 2 + half) ^ prh) * 8));
    // PV: O[32 x 256] += P[32 x 64] @ V[64 x 256]
#pragma unroll
    for (int ct = 0; ct < 8; ++ct) {
      int ch = ct * 32 + n32;
      const unsigned short* vbase = Vt + ch * 64;
      int crh = ch & 7;
#pragma unroll
      for (int ks = 0; ks < 4; ++ks) {
        s16x8 vf = *(const s16x8*)(vbase + (((ks * 2 + half) ^ crh) * 8));
        Oa[ct] = __builtin_amdgcn_mfma_f32_32x32x16_bf16(pf[ks], vf, Oa[ct], 0, 0, 0);
      }
    }
    __syncthreads();   // all reads done before next stage overwrites
  }
  // epilogue: unnormalized O (bf16) + row sums l
#pragma unroll
  for (int ct = 0; ct < 8; ++ct)
#pragma unroll
    for (int r = 0; r < 16; ++r) {
      int row = (r & 3) + 8 * (r >> 2) + 4 * half;
      op[(size_t)(qrow0 + row) * C_DIM + ct * 32 + n32] = f2bf(Oa[ct][r]);
    }
#pragma unroll
  for (int r = 0; r < 16; ++r) {
    float v = ls[r];
    v += __shfl_xor(v, 1); v += __shfl_xor(v, 2); v += __shfl_xor(v, 4);
    v += __shfl_xor(v, 8); v += __shfl_xor(v, 16);
    if (n32 == 0) {
      int row = (r & 3) + 8 * (r >> 2) + 4 * half;
      lbuf[chunk * M_ROWS + qrow0 + row] = v;
    }
  }
}

// ------- Output projection (fused combine) + bias + residual -> fp32 out ------
// A = (sum of 4 unnormalized O planes) / (sum of 4 l partials), built in regs.
__global__ __launch_bounds__(256) void proj_gemm(const unsigned short* __restrict__ p0,
                                                 const unsigned short* __restrict__ p1,
                                                 const unsigned short* __restrict__ p2,
                                                 const unsigned short* __restrict__ p3,
                                                 const float* __restrict__ lbuf,
                                                 const unsigned short* __restrict__ wt,
                                                 const float* __restrict__ bp,
                                                 const float* __restrict__ x,
                                                 float* __restrict__ out) {
  int tid = threadIdx.x;
  int wave = tid >> 6, lane = tid & 63, g = lane >> 4, c16 = lane & 15;
  int row0 = blockIdx.x * 64 + wave * 16;
  int ct0 = blockIdx.y * 8;
  int row = row0 + c16;
  float linv = 1.f / (lbuf[row] + lbuf[M_ROWS + row] +
                      lbuf[2 * M_ROWS + row] + lbuf[3 * M_ROWS + row]);
  s16x8 af[8];
#pragma unroll
  for (int s = 0; s < 8; ++s) {
    size_t off = (size_t)row * C_DIM + s * 32 + g * 8;
    s16x8 a0 = *(const s16x8*)(p0 + off);
    s16x8 a1 = *(const s16x8*)(p1 + off);
    s16x8 a2 = *(const s16x8*)(p2 + off);
    s16x8 a3 = *(const s16x8*)(p3 + off);
    s16x8 o;
#pragma unroll
    for (int j = 0; j < 8; ++j) {
      float f = bf2f((unsigned short)a0[j]) + bf2f((unsigned short)a1[j]) +
                bf2f((unsigned short)a2[j]) + bf2f((unsigned short)a3[j]);
      o[j] = (short)f2bf(f * linv);
    }
    af[s] = o;
  }
  for (int ct = ct0; ct < ct0 + 8; ++ct) {
    float bias = bp[ct * 16 + c16];
    f32x4 acc = {bias, bias, bias, bias};
#pragma unroll
    for (int s = 0; s < 8; ++s) {
      s16x8 bf = *(const s16x8*)(wt + (ct * 16 + c16) * C_DIM + s * 32 + g * 8);
      acc = __builtin_amdgcn_mfma_f32_16x16x32_bf16(af[s], bf, acc, 0, 0, 0);
    }
#pragma unroll
    for (int r = 0; r < 4; ++r) {
      int idx = (row0 + g * 4 + r) * C_DIM + ct * 16 + c16;
      out[idx] = acc[r] + x[idx];
    }
  }
}

extern "C" void kernel_launch(void* const* d_in, const int* in_sizes, int n_in,
                              void* d_out, int out_size, void* d_ws, size_t ws_size,
                              hipStream_t stream) {
  const float* x     = (const float*)d_in[0];
  const float* gamma = (const float*)d_in[1];
  const float* beta  = (const float*)d_in[2];
  const float* wq    = (const float*)d_in[3];
  const float* bq    = (const float*)d_in[4];
  const float* wk    = (const float*)d_in[5];
  const float* bk    = (const float*)d_in[6];
  const float* wv    = (const float*)d_in[7];
  const float* bv    = (const float*)d_in[8];
  const float* wp    = (const float*)d_in[9];
  const float* bp    = (const float*)d_in[10];
  float* out = (float*)d_out;

  char* ws = (char*)d_ws;
  const size_t MC = (size_t)M_ROWS * C_DIM;
  float* partials      = (float*)ws;                          // 64 floats
  unsigned short* wT   = (unsigned short*)(ws + 1024);        // 4 x 256x256 bf16
  unsigned short* xnb  = wT + 4 * 65536;                      // xn bf16 [16384,256]
  unsigned short* qb   = xnb + MC;
  unsigned short* kbuf = qb + MC;
  unsigned short* vb   = kbuf + MC;
  unsigned short* vTb  = vb + MC;
  unsigned short* exA  = vTb + MC;                            // O partial planes 2,3
  unsigned short* exB  = exA + MC;
  float* lbuf          = (float*)(exB + MC);                  // 4 x 16384 floats
  // O partial planes: 0 -> xnb (dead after qkv), 1 -> vb (dead after vtrans)
  unsigned short* plane0 = xnb;
  unsigned short* plane1 = vb;

  hipMemsetAsync(partials, 0, 64 * sizeof(float), stream);
  wtrans<<<dim3(8, 8, 4), dim3(32, 8), 0, stream>>>(wq, wk, wv, wp, wT);
  gn_stats<<<512, 256, 0, stream>>>(x, partials);
  gn_norm<<<1024, 256, 0, stream>>>(x, gamma, beta, partials, xnb);
  qkv_gemm<<<dim3(256, 3), 256, 0, stream>>>(xnb, wT, bq, bk, bv, qb, kbuf, vb);
  vtrans<<<dim3(128, 8, 4), dim3(32, 8), 0, stream>>>(vb, vTb);
  attn_part<<<512, 256, 0, stream>>>(qb, kbuf, vTb, plane0, plane1, exA, exB, lbuf);
  proj_gemm<<<dim3(256, 2), 256, 0, stream>>>(plane0, plane1, exA, exB, lbuf,
                                              wT + 3 * 65536, bp, x, out);
}